// Round 12
// baseline (86.935 us; speedup 1.0000x reference)
//
#include <hip/hip_runtime.h>
#include <hip/hip_bf16.h>

#define NATOMS 262144
#define NG     8192
#define FDIM   128
#define NELEM  118
#define EPS    1e-6f
#define TROWS  1024          // table rows per idx (1023 intervals)
#define NBLK_SCAN 3776       // 3776 * 2048 float4 = 7,733,248 = NATOMS*NELEM/4
#define INTERP_BLOCKS 4096
#define INTERP_THREADS (INTERP_BLOCKS * 256)   // 1,048,576; x8 = NATOMS*32

typedef __attribute__((ext_vector_type(8))) short bf16x8;
typedef __attribute__((ext_vector_type(4))) float f32x4;

__device__ __forceinline__ float silu_fast(float v) {
    return v * __builtin_amdgcn_rcpf(1.f + __expf(-v));
}
// truncation-based hi/lo split of two floats -> packed u32 (hi pair, lo pair)
__device__ __forceinline__ void split2(float x0, float x1,
                                       unsigned& hpack, unsigned& lpack) {
    unsigned u0 = __float_as_uint(x0), u1 = __float_as_uint(x1);
    unsigned h0m = u0 & 0xFFFF0000u, h1m = u1 & 0xFFFF0000u;
    hpack = (u0 >> 16) | h1m;
    float l0 = x0 - __uint_as_float(h0m);
    float l1 = x1 - __uint_as_float(h1m);
    lpack = (__float_as_uint(l0) >> 16) | (__float_as_uint(l1) & 0xFFFF0000u);
}
// swizzled LDS offset (u16 elems): row stride 128, 16B-granule XOR swizzle
__device__ __forceinline__ int aoff(int row, int k) {
    return row * FDIM + ((((k >> 3) ^ row) & 15) << 3) + (k & 7);
}

// ---------------------------------------------------------------------------
// Dispatch 1: blocks 0..3775 = z-scan (8 plain float4 per thread, 128B);
// tail blocks = prep (softplus T, denom/ymin/ymax init).
// ---------------------------------------------------------------------------
__global__ void zscan_prep_kernel(const f32x4* __restrict__ onehot4,
                                  int* __restrict__ z,
                                  const float* __restrict__ Wq,
                                  const float* __restrict__ Wk,
                                  float* __restrict__ T,
                                  float* __restrict__ denom,
                                  unsigned* __restrict__ yminE,
                                  unsigned* __restrict__ ymaxE) {
    int b = blockIdx.x, t = threadIdx.x;
    if (b < NBLK_SCAN) {
        int base = b * 2048 + t;
        f32x4 v[8];
        #pragma unroll
        for (int k = 0; k < 8; ++k)
            v[k] = onehot4[base + k * 256];
        #pragma unroll
        for (int k = 0; k < 8; ++k) {
            int i4 = (base + k * 256) * 4;
            #pragma unroll
            for (int q = 0; q < 4; ++q)
                if (v[k][q] > 0.5f) {
                    int gf = i4 + q;
                    int n  = gf / NELEM;
                    z[n] = gf - n * NELEM;
                }
        }
    } else {
        int pb = b - NBLK_SCAN;
        if (pb == 0) {
            if (t < 2 * NELEM) {
                int idx = t / NELEM;
                int zz  = t - idx * NELEM;
                float dot = 0.f;
                #pragma unroll 8
                for (int f = 0; f < FDIM; ++f)
                    dot += Wq[f * NELEM + zz] * Wk[idx * FDIM + f];
                float x = dot * 0.08838834764831843f;  // 1/sqrt(128)
                T[t] = fmaxf(x, 0.f) + log1pf(expf(-fabsf(x)));
            }
        } else {
            int j = (pb - 1) * 256 + t; // 0..24575
            if (j < NG)            denom[j] = 0.f;
            else if (j < 2 * NG)   ymaxE[j - NG] = 0u;               // y > 0
            else                   yminE[j - 2 * NG] = 0xFFFFFFFFu;  // raw max
        }
    }
}

// ---------------------------------------------------------------------------
// Dispatch 2: y[n] = T[idx(g)][z[n]] (coalesced); segmented {sum,min,max}
// per graph via wave scan; spread boundary atomics.
// ---------------------------------------------------------------------------
__global__ void stat_kernel(const int* __restrict__ seg,
                            const float* __restrict__ psi,
                            const float* __restrict__ T,
                            const int* __restrict__ z,
                            float* __restrict__ y_out,
                            float* __restrict__ denom,
                            unsigned* __restrict__ yminE,
                            unsigned* __restrict__ ymaxE) {
    int n = blockIdx.x * blockDim.x + threadIdx.x;
    int g = seg[n];
    int idx = psi[g] < 0.f ? 1 : 0;
    float yv = T[idx * NELEM + z[n]];
    y_out[n] = yv;

    int lane = threadIdx.x & 63;
    float s = yv, mn = yv, mx = yv;
    #pragma unroll
    for (int d = 1; d < 64; d <<= 1) {
        float os = __shfl_up(s,  (unsigned)d, 64);
        float on = __shfl_up(mn, (unsigned)d, 64);
        float ox = __shfl_up(mx, (unsigned)d, 64);
        int   go = __shfl_up(g,  (unsigned)d, 64);
        if (lane >= d && go == g) {
            s += os;
            mn = fminf(mn, on);
            mx = fmaxf(mx, ox);
        }
    }
    int gn = __shfl_down(g, 1u, 64);
    if (lane == 63 || gn != g) {
        atomicAdd(&denom[g], s);
        atomicMin(&yminE[g], __float_as_uint(mn));   // y > 0: raw-uint order ok
        atomicMax(&ymaxE[g], __float_as_uint(mx));
    }
}

// ---------------------------------------------------------------------------
// Dispatch 3: range-reduce prologue (redundant per block) -> prm; write
// q[g] = psi/(denom+eps)*p2 (16 blk x 512 thr = 8192); split-bf16 MFMA MLP
// over 2048 virtual atoms -> tbl. Weights split to bf16 hi/lo in registers.
// ---------------------------------------------------------------------------
__launch_bounds__(512, 4)
__global__ void mlp_table_kernel(const float* __restrict__ psi_g,
                                 const float* __restrict__ denom,
                                 const unsigned* __restrict__ yminE,
                                 const unsigned* __restrict__ ymaxE,
                                 const float* __restrict__ Wv,
                                 const float* __restrict__ W1,
                                 const float* __restrict__ W2,
                                 float* __restrict__ tbl,
                                 float* __restrict__ prm,
                                 float* __restrict__ q) {
    __shared__ __align__(16) unsigned short Ahi[FDIM * FDIM];
    __shared__ __align__(16) unsigned short Alo[FDIM * FDIM];
    __shared__ float att_s[128];
    __shared__ int   idx_s[128];
    __shared__ float wv_s[2 * FDIM];
    __shared__ float smn[8], smx[8], prm_s[3];

    int t    = threadIdx.x;
    int lane = t & 63;
    int w    = t >> 6;

    // ---- range reduction over graphs (identical in every block) ----
    {
        float mn = 1e30f, mx = -1e30f;
        for (int j = t; j < NG; j += 512) {
            unsigned me = yminE[j];
            if (me != 0xFFFFFFFFu) {           // graph has atoms
                float r  = __builtin_amdgcn_rcpf(denom[j] + EPS);
                float ps = psi_g[j];
                float a1 = ps * __uint_as_float(me) * r;
                float a2 = ps * __uint_as_float(ymaxE[j]) * r;
                mn = fminf(mn, fminf(a1, a2));
                mx = fmaxf(mx, fmaxf(a1, a2));
            }
        }
        #pragma unroll
        for (int d = 32; d > 0; d >>= 1) {
            mn = fminf(mn, __shfl_xor(mn, d, 64));
            mx = fmaxf(mx, __shfl_xor(mx, d, 64));
        }
        if (lane == 0) { smn[w] = mn; smx[w] = mx; }
        __syncthreads();
        if (t == 0) {
            mn = smn[0]; mx = smx[0];
            #pragma unroll
            for (int qq = 1; qq < 8; ++qq) {
                mn = fminf(mn, smn[qq]);
                mx = fmaxf(mx, smx[qq]);
            }
            float range = mx - mn;
            if (!(range > 0.f)) range = 1.f;
            float p2 = (float)(TROWS - 1) / range;
            prm_s[0] = mn;
            prm_s[1] = range / (float)(TROWS - 1);
            prm_s[2] = p2;
            if (blockIdx.x == 0) {
                prm[0] = mn;
                prm[1] = prm_s[1];
                prm[2] = p2;
                prm[3] = mn * p2;   // cB
            }
        }
        __syncthreads();
    }
    float p0 = prm_s[0], hh = prm_s[1], p2 = prm_s[2];

    // ---- q[g] write: 16 blocks x 512 threads = 8192 graphs ----
    {
        int g = blockIdx.x * 512 + t;
        q[g] = psi_g[g] * __builtin_amdgcn_rcpf(denom[g] + EPS) * p2;
    }

    int wr   = w >> 2;
    int wc   = w & 3;
    int n0   = blockIdx.x * 128;
    int rbase = wr * 64;
    int jbase = wc * 32;

    if (t < 256) wv_s[t] = Wv[t];
    if (t >= 256 && t < 384) {
        int a = t - 256;
        int n = n0 + a;
        idx_s[a] = n >> 10;
        att_s[a] = p0 + (float)(n & (TROWS - 1)) * hh;
    }
    __syncthreads();

    {
        int a  = t >> 2;
        int kq = (t & 3) * 32;
        float att = att_s[a];
        const float* wvp = &wv_s[idx_s[a] * FDIM + kq];
        #pragma unroll
        for (int kk = 0; kk < 32; kk += 2) {
            float s0 = silu_fast(att * wvp[kk]);
            float s1 = silu_fast(att * wvp[kk + 1]);
            unsigned hp, lp;
            split2(s0, s1, hp, lp);
            int off = aoff(a, kq + kk);
            *(unsigned*)&Ahi[off] = hp;
            *(unsigned*)&Alo[off] = lp;
        }
    }
    __syncthreads();

    int lrow = lane & 15;
    int k0   = (lane >> 4) * 8;

    f32x4 acc[4][2];

    #pragma unroll
    for (int L = 0; L < 2; ++L) {
        const float* Wf = (L == 0) ? W1 : W2;

        #pragma unroll
        for (int mt = 0; mt < 4; ++mt)
            #pragma unroll
            for (int jt = 0; jt < 2; ++jt)
                acc[mt][jt] = (f32x4){0.f, 0.f, 0.f, 0.f};

        #pragma unroll
        for (int kt = 0; kt < 4; ++kt) {
            bf16x8 bh[2], bl[2];
            #pragma unroll
            for (int jt = 0; jt < 2; ++jt) {
                int j = jbase + jt * 16 + lrow;
                const f32x4* wp = (const f32x4*)&Wf[j * FDIM + kt * 32 + k0];
                f32x4 wa = wp[0], wb = wp[1];
                union { unsigned u[4]; bf16x8 v; } H, L8;
                split2(wa[0], wa[1], H.u[0], L8.u[0]);
                split2(wa[2], wa[3], H.u[1], L8.u[1]);
                split2(wb[0], wb[1], H.u[2], L8.u[2]);
                split2(wb[2], wb[3], H.u[3], L8.u[3]);
                bh[jt] = H.v; bl[jt] = L8.v;
            }
            #pragma unroll
            for (int mt = 0; mt < 4; ++mt) {
                int off = aoff(rbase + mt * 16 + lrow, kt * 32 + k0);
                bf16x8 ah = *(const bf16x8*)&Ahi[off];
                bf16x8 al = *(const bf16x8*)&Alo[off];
                #pragma unroll
                for (int jt = 0; jt < 2; ++jt) {
                    acc[mt][jt] = __builtin_amdgcn_mfma_f32_16x16x32_bf16(ah, bh[jt], acc[mt][jt], 0, 0, 0);
                    acc[mt][jt] = __builtin_amdgcn_mfma_f32_16x16x32_bf16(ah, bl[jt], acc[mt][jt], 0, 0, 0);
                    acc[mt][jt] = __builtin_amdgcn_mfma_f32_16x16x32_bf16(al, bh[jt], acc[mt][jt], 0, 0, 0);
                }
            }
        }

        if (L == 0) {
            __syncthreads();
            #pragma unroll
            for (int mt = 0; mt < 4; ++mt)
                #pragma unroll
                for (int jt = 0; jt < 2; ++jt)
                    #pragma unroll
                    for (int r = 0; r < 4; ++r) {
                        int row = rbase + mt * 16 + (lane >> 4) * 4 + r;
                        int col = jbase + jt * 16 + lrow;
                        float s = silu_fast(acc[mt][jt][r]);
                        unsigned u = __float_as_uint(s);
                        unsigned hm = u & 0xFFFF0000u;
                        float l = s - __uint_as_float(hm);
                        int off = aoff(row, col);
                        Ahi[off] = (unsigned short)(u >> 16);
                        Alo[off] = (unsigned short)(__float_as_uint(l) >> 16);
                    }
            __syncthreads();
        }
    }

    // tbl row = f(att) = v_att + h2
    #pragma unroll
    for (int mt = 0; mt < 4; ++mt)
        #pragma unroll
        for (int jt = 0; jt < 2; ++jt) {
            int row0 = rbase + mt * 16 + (lane >> 4) * 4;
            int col  = jbase + jt * 16 + lrow;
            float* p = tbl + (long)(n0 + row0) * FDIM + col;
            #pragma unroll
            for (int r = 0; r < 4; ++r) {
                int row = row0 + r;
                float vatt = att_s[row] * wv_s[idx_s[row] * FDIM + col];
                p[r * FDIM] = acc[mt][jt][r] + vatt;
            }
        }
}

// ---------------------------------------------------------------------------
// Dispatch 4: out[n][:] = lerp(tbl[idx][b], tbl[idx][b+1], t). 32 lanes/atom.
// Fully unrolled x8 (grid fixed 4096x256): 8 dependent chains in flight.
// ---------------------------------------------------------------------------
__global__ void interp_kernel(const int* __restrict__ seg,
                              const float* __restrict__ y,
                              const float* __restrict__ q,
                              const float* __restrict__ prm,
                              const float* __restrict__ tbl,
                              float* __restrict__ out) {
    float cB = prm[3];
    int tid = blockIdx.x * 256 + threadIdx.x;

    int   nn[8], jq[8];
    float qv[8], yv[8];
    #pragma unroll
    for (int k = 0; k < 8; ++k) {
        int i = tid + k * INTERP_THREADS;
        nn[k] = i >> 5;
        jq[k] = i & 31;
    }
    int gg[8];
    #pragma unroll
    for (int k = 0; k < 8; ++k) gg[k] = seg[nn[k]];
    #pragma unroll
    for (int k = 0; k < 8; ++k) { qv[k] = q[gg[k]]; yv[k] = y[nn[k]]; }

    const f32x4* r0[8];
    float tt[8];
    #pragma unroll
    for (int k = 0; k < 8; ++k) {
        float x = fmaf(yv[k], qv[k], -cB);
        int idx = (int)(__float_as_uint(qv[k]) >> 31);
        int b = (int)floorf(x);
        b = min(max(b, 0), TROWS - 2);
        tt[k] = x - (float)b;
        r0[k] = (const f32x4*)&tbl[(long)((idx << 10) + b) * FDIM];
    }
    f32x4 a[8], c[8];
    #pragma unroll
    for (int k = 0; k < 8; ++k) {
        a[k] = r0[k][jq[k]];
        c[k] = r0[k][jq[k] + 32];   // next row (+128 floats)
    }
    #pragma unroll
    for (int k = 0; k < 8; ++k) {
        f32x4 o;
        float t = tt[k];
        o[0] = a[k][0] + t * (c[k][0] - a[k][0]);
        o[1] = a[k][1] + t * (c[k][1] - a[k][1]);
        o[2] = a[k][2] + t * (c[k][2] - a[k][2]);
        o[3] = a[k][3] + t * (c[k][3] - a[k][3]);
        __builtin_nontemporal_store(o, (f32x4*)&out[(long)nn[k] * FDIM + jq[k] * 4]);
    }
}

// ---------------------------------------------------------------------------
extern "C" void kernel_launch(void* const* d_in, const int* in_sizes, int n_in,
                              void* d_out, int out_size, void* d_ws, size_t ws_size,
                              hipStream_t stream) {
    const float* onehot = (const float*)d_in[0];
    const float* psi    = (const float*)d_in[1];
    const float* Wq     = (const float*)d_in[2];
    const float* Wk     = (const float*)d_in[3];
    const float* Wv     = (const float*)d_in[4];
    const float* W1     = (const float*)d_in[5];
    const float* W2     = (const float*)d_in[6];
    const int*   seg    = (const int*)d_in[7];
    float*       out    = (float*)d_out;

    // workspace layout (tbl aliases z: z is dead after stat_kernel)
    char* ws = (char*)d_ws;
    float*    denom = (float*)ws;                         // 32KB
    unsigned* ymaxE = (unsigned*)(ws + 32768);            // 32KB
    unsigned* yminE = (unsigned*)(ws + 65536);            // 32KB
    float*    T     = (float*)(ws + 98304);               // 1KB
    float*    prm   = (float*)(ws + 99328);               // 16B
    float*    q     = (float*)(ws + 100352);              // 32KB
    float*    y     = (float*)(ws + 133120);              // 1MB
    int*      z     = (int*)(ws + 133120 + NATOMS * 4);   // 1MB
    float*    tbl   = (float*)(ws + 133120 + NATOMS * 4); // 1MB (alias z)

    zscan_prep_kernel<<<NBLK_SCAN + 97, 256, 0, stream>>>(
        (const f32x4*)onehot, z, Wq, Wk, T, denom, yminE, ymaxE);

    stat_kernel<<<NATOMS / 256, 256, 0, stream>>>(seg, psi, T, z, y,
                                                  denom, yminE, ymaxE);

    mlp_table_kernel<<<2 * TROWS / 128, 512, 0, stream>>>(psi, denom, yminE, ymaxE,
                                                          Wv, W1, W2, tbl, prm, q);

    interp_kernel<<<INTERP_BLOCKS, 256, 0, stream>>>(seg, y, q, prm, tbl, out);
}

// Round 13
// 83.725 us; speedup vs baseline: 1.0383x; 1.0383x over previous
//
#include <hip/hip_runtime.h>
#include <hip/hip_bf16.h>

#define NATOMS 262144
#define NG     8192
#define FDIM   128
#define NELEM  118
#define EPS    1e-6f
#define TROWS  1024          // table rows per idx (1023 intervals)
#define NBLK_SCAN 7552       // 7552 * 1024 float4 = 7,733,248 = NATOMS*NELEM/4
#define INTERP_BLOCKS 4096
#define INTERP_THREADS (INTERP_BLOCKS * 256)   // 1,048,576; x8 = NATOMS*32

typedef __attribute__((ext_vector_type(8))) short bf16x8;
typedef __attribute__((ext_vector_type(4))) float f32x4;

__device__ __forceinline__ float silu_fast(float v) {
    return v * __builtin_amdgcn_rcpf(1.f + __expf(-v));
}
// truncation-based hi/lo split of two floats -> packed u32 (hi pair, lo pair)
__device__ __forceinline__ void split2(float x0, float x1,
                                       unsigned& hpack, unsigned& lpack) {
    unsigned u0 = __float_as_uint(x0), u1 = __float_as_uint(x1);
    unsigned h0m = u0 & 0xFFFF0000u, h1m = u1 & 0xFFFF0000u;
    hpack = (u0 >> 16) | h1m;
    float l0 = x0 - __uint_as_float(h0m);
    float l1 = x1 - __uint_as_float(h1m);
    lpack = (__float_as_uint(l0) >> 16) | (__float_as_uint(l1) & 0xFFFF0000u);
}
// swizzled LDS offset (u16 elems): row stride 128, 16B-granule XOR swizzle
__device__ __forceinline__ int aoff(int row, int k) {
    return row * FDIM + ((((k >> 3) ^ row) & 15) << 3) + (k & 7);
}

// ---------------------------------------------------------------------------
// Dispatch 1: blocks 0..7551 = z-scan (4 independent NT float4 per thread);
// tail blocks = prep (softplus T, denom/ymin/ymax init).  [R11-proven]
// ---------------------------------------------------------------------------
__global__ void zscan_prep_kernel(const f32x4* __restrict__ onehot4,
                                  int* __restrict__ z,
                                  const float* __restrict__ Wq,
                                  const float* __restrict__ Wk,
                                  float* __restrict__ T,
                                  float* __restrict__ denom,
                                  unsigned* __restrict__ yminE,
                                  unsigned* __restrict__ ymaxE) {
    int b = blockIdx.x, t = threadIdx.x;
    if (b < NBLK_SCAN) {
        int base = b * 1024 + t;
        f32x4 v[4];
        #pragma unroll
        for (int k = 0; k < 4; ++k)
            v[k] = __builtin_nontemporal_load(&onehot4[base + k * 256]);
        #pragma unroll
        for (int k = 0; k < 4; ++k) {
            int i4 = (base + k * 256) * 4;
            #pragma unroll
            for (int q = 0; q < 4; ++q)
                if (v[k][q] > 0.5f) {
                    int gf = i4 + q;
                    int n  = gf / NELEM;
                    z[n] = gf - n * NELEM;
                }
        }
    } else {
        int pb = b - NBLK_SCAN;
        if (pb == 0) {
            if (t < 2 * NELEM) {
                int idx = t / NELEM;
                int zz  = t - idx * NELEM;
                float dot = 0.f;
                #pragma unroll 8
                for (int f = 0; f < FDIM; ++f)
                    dot += Wq[f * NELEM + zz] * Wk[idx * FDIM + f];
                float x = dot * 0.08838834764831843f;  // 1/sqrt(128)
                T[t] = fmaxf(x, 0.f) + log1pf(expf(-fabsf(x)));
            }
        } else {
            int j = (pb - 1) * 256 + t; // 0..24575
            if (j < NG)            denom[j] = 0.f;
            else if (j < 2 * NG)   ymaxE[j - NG] = 0u;               // y > 0
            else                   yminE[j - 2 * NG] = 0xFFFFFFFFu;  // raw max
        }
    }
}

// ---------------------------------------------------------------------------
// Dispatch 2: y[n] = T[idx(g)][z[n]] (coalesced); segmented {sum,min,max}
// per graph via wave scan; spread boundary atomics.  [R11-proven]
// ---------------------------------------------------------------------------
__global__ void stat_kernel(const int* __restrict__ seg,
                            const float* __restrict__ psi,
                            const float* __restrict__ T,
                            const int* __restrict__ z,
                            float* __restrict__ y_out,
                            float* __restrict__ denom,
                            unsigned* __restrict__ yminE,
                            unsigned* __restrict__ ymaxE) {
    int n = blockIdx.x * blockDim.x + threadIdx.x;
    int g = seg[n];
    int idx = psi[g] < 0.f ? 1 : 0;
    float yv = T[idx * NELEM + z[n]];
    y_out[n] = yv;

    int lane = threadIdx.x & 63;
    float s = yv, mn = yv, mx = yv;
    #pragma unroll
    for (int d = 1; d < 64; d <<= 1) {
        float os = __shfl_up(s,  (unsigned)d, 64);
        float on = __shfl_up(mn, (unsigned)d, 64);
        float ox = __shfl_up(mx, (unsigned)d, 64);
        int   go = __shfl_up(g,  (unsigned)d, 64);
        if (lane >= d && go == g) {
            s += os;
            mn = fminf(mn, on);
            mx = fmaxf(mx, ox);
        }
    }
    int gn = __shfl_down(g, 1u, 64);
    if (lane == 63 || gn != g) {
        atomicAdd(&denom[g], s);
        atomicMin(&yminE[g], __float_as_uint(mn));   // y > 0: raw-uint order ok
        atomicMax(&ymaxE[g], __float_as_uint(mx));
    }
}

// ---------------------------------------------------------------------------
// Dispatch 3: range-reduce prologue (redundant per block) -> prm; write
// q[g] = psi/(denom+eps)*p2 (16 blk x 512 thr = 8192); split-bf16 MFMA MLP
// over 2048 virtual atoms -> tbl. Weights split to bf16 hi/lo in registers.
// ---------------------------------------------------------------------------
__launch_bounds__(512, 4)
__global__ void mlp_table_kernel(const float* __restrict__ psi_g,
                                 const float* __restrict__ denom,
                                 const unsigned* __restrict__ yminE,
                                 const unsigned* __restrict__ ymaxE,
                                 const float* __restrict__ Wv,
                                 const float* __restrict__ W1,
                                 const float* __restrict__ W2,
                                 float* __restrict__ tbl,
                                 float* __restrict__ prm,
                                 float* __restrict__ q) {
    __shared__ __align__(16) unsigned short Ahi[FDIM * FDIM];
    __shared__ __align__(16) unsigned short Alo[FDIM * FDIM];
    __shared__ float att_s[128];
    __shared__ int   idx_s[128];
    __shared__ float wv_s[2 * FDIM];
    __shared__ float smn[8], smx[8], prm_s[3];

    int t    = threadIdx.x;
    int lane = t & 63;
    int w    = t >> 6;

    // ---- range reduction over graphs (identical in every block) ----
    {
        float mn = 1e30f, mx = -1e30f;
        for (int j = t; j < NG; j += 512) {
            unsigned me = yminE[j];
            if (me != 0xFFFFFFFFu) {           // graph has atoms
                float r  = __builtin_amdgcn_rcpf(denom[j] + EPS);
                float ps = psi_g[j];
                float a1 = ps * __uint_as_float(me) * r;
                float a2 = ps * __uint_as_float(ymaxE[j]) * r;
                mn = fminf(mn, fminf(a1, a2));
                mx = fmaxf(mx, fmaxf(a1, a2));
            }
        }
        #pragma unroll
        for (int d = 32; d > 0; d >>= 1) {
            mn = fminf(mn, __shfl_xor(mn, d, 64));
            mx = fmaxf(mx, __shfl_xor(mx, d, 64));
        }
        if (lane == 0) { smn[w] = mn; smx[w] = mx; }
        __syncthreads();
        if (t == 0) {
            mn = smn[0]; mx = smx[0];
            #pragma unroll
            for (int qq = 1; qq < 8; ++qq) {
                mn = fminf(mn, smn[qq]);
                mx = fmaxf(mx, smx[qq]);
            }
            float range = mx - mn;
            if (!(range > 0.f)) range = 1.f;
            float p2 = (float)(TROWS - 1) / range;
            prm_s[0] = mn;
            prm_s[1] = range / (float)(TROWS - 1);
            prm_s[2] = p2;
            if (blockIdx.x == 0) {
                prm[0] = mn;
                prm[1] = prm_s[1];
                prm[2] = p2;
                prm[3] = mn * p2;   // cB
            }
        }
        __syncthreads();
    }
    float p0 = prm_s[0], hh = prm_s[1], p2 = prm_s[2];

    // ---- q[g] write: 16 blocks x 512 threads = 8192 graphs ----
    {
        int g = blockIdx.x * 512 + t;
        q[g] = psi_g[g] * __builtin_amdgcn_rcpf(denom[g] + EPS) * p2;
    }

    int wr   = w >> 2;
    int wc   = w & 3;
    int n0   = blockIdx.x * 128;
    int rbase = wr * 64;
    int jbase = wc * 32;

    if (t < 256) wv_s[t] = Wv[t];
    if (t >= 256 && t < 384) {
        int a = t - 256;
        int n = n0 + a;
        idx_s[a] = n >> 10;
        att_s[a] = p0 + (float)(n & (TROWS - 1)) * hh;
    }
    __syncthreads();

    {
        int a  = t >> 2;
        int kq = (t & 3) * 32;
        float att = att_s[a];
        const float* wvp = &wv_s[idx_s[a] * FDIM + kq];
        #pragma unroll
        for (int kk = 0; kk < 32; kk += 2) {
            float s0 = silu_fast(att * wvp[kk]);
            float s1 = silu_fast(att * wvp[kk + 1]);
            unsigned hp, lp;
            split2(s0, s1, hp, lp);
            int off = aoff(a, kq + kk);
            *(unsigned*)&Ahi[off] = hp;
            *(unsigned*)&Alo[off] = lp;
        }
    }
    __syncthreads();

    int lrow = lane & 15;
    int k0   = (lane >> 4) * 8;

    f32x4 acc[4][2];

    #pragma unroll
    for (int L = 0; L < 2; ++L) {
        const float* Wf = (L == 0) ? W1 : W2;

        #pragma unroll
        for (int mt = 0; mt < 4; ++mt)
            #pragma unroll
            for (int jt = 0; jt < 2; ++jt)
                acc[mt][jt] = (f32x4){0.f, 0.f, 0.f, 0.f};

        #pragma unroll
        for (int kt = 0; kt < 4; ++kt) {
            bf16x8 bh[2], bl[2];
            #pragma unroll
            for (int jt = 0; jt < 2; ++jt) {
                int j = jbase + jt * 16 + lrow;
                const f32x4* wp = (const f32x4*)&Wf[j * FDIM + kt * 32 + k0];
                f32x4 wa = wp[0], wb = wp[1];
                union { unsigned u[4]; bf16x8 v; } H, L8;
                split2(wa[0], wa[1], H.u[0], L8.u[0]);
                split2(wa[2], wa[3], H.u[1], L8.u[1]);
                split2(wb[0], wb[1], H.u[2], L8.u[2]);
                split2(wb[2], wb[3], H.u[3], L8.u[3]);
                bh[jt] = H.v; bl[jt] = L8.v;
            }
            #pragma unroll
            for (int mt = 0; mt < 4; ++mt) {
                int off = aoff(rbase + mt * 16 + lrow, kt * 32 + k0);
                bf16x8 ah = *(const bf16x8*)&Ahi[off];
                bf16x8 al = *(const bf16x8*)&Alo[off];
                #pragma unroll
                for (int jt = 0; jt < 2; ++jt) {
                    acc[mt][jt] = __builtin_amdgcn_mfma_f32_16x16x32_bf16(ah, bh[jt], acc[mt][jt], 0, 0, 0);
                    acc[mt][jt] = __builtin_amdgcn_mfma_f32_16x16x32_bf16(ah, bl[jt], acc[mt][jt], 0, 0, 0);
                    acc[mt][jt] = __builtin_amdgcn_mfma_f32_16x16x32_bf16(al, bh[jt], acc[mt][jt], 0, 0, 0);
                }
            }
        }

        if (L == 0) {
            __syncthreads();
            #pragma unroll
            for (int mt = 0; mt < 4; ++mt)
                #pragma unroll
                for (int jt = 0; jt < 2; ++jt)
                    #pragma unroll
                    for (int r = 0; r < 4; ++r) {
                        int row = rbase + mt * 16 + (lane >> 4) * 4 + r;
                        int col = jbase + jt * 16 + lrow;
                        float s = silu_fast(acc[mt][jt][r]);
                        unsigned u = __float_as_uint(s);
                        unsigned hm = u & 0xFFFF0000u;
                        float l = s - __uint_as_float(hm);
                        int off = aoff(row, col);
                        Ahi[off] = (unsigned short)(u >> 16);
                        Alo[off] = (unsigned short)(__float_as_uint(l) >> 16);
                    }
            __syncthreads();
        }
    }

    // tbl row = f(att) = v_att + h2
    #pragma unroll
    for (int mt = 0; mt < 4; ++mt)
        #pragma unroll
        for (int jt = 0; jt < 2; ++jt) {
            int row0 = rbase + mt * 16 + (lane >> 4) * 4;
            int col  = jbase + jt * 16 + lrow;
            float* p = tbl + (long)(n0 + row0) * FDIM + col;
            #pragma unroll
            for (int r = 0; r < 4; ++r) {
                int row = row0 + r;
                float vatt = att_s[row] * wv_s[idx_s[row] * FDIM + col];
                p[r * FDIM] = acc[mt][jt][r] + vatt;
            }
        }
}

// ---------------------------------------------------------------------------
// Dispatch 4: out[n][:] = lerp(tbl[idx][b], tbl[idx][b+1], t). 32 lanes/atom.
// Grid-stride (R11 form) with 2 independent chains per iteration (mild ILP,
// low VGPR cost — R12's x8 unroll killed occupancy).
// ---------------------------------------------------------------------------
__global__ void interp_kernel(const int* __restrict__ seg,
                              const float* __restrict__ y,
                              const float* __restrict__ q,
                              const float* __restrict__ prm,
                              const float* __restrict__ tbl,
                              float* __restrict__ out) {
    float cB = prm[3];
    int tid = blockIdx.x * 256 + threadIdx.x;

    #pragma unroll
    for (int k = 0; k < 4; ++k) {
        int i0 = tid + (2 * k) * INTERP_THREADS;
        int i1 = tid + (2 * k + 1) * INTERP_THREADS;
        int n0 = i0 >> 5, j0 = i0 & 31;
        int n1 = i1 >> 5, j1 = i1 & 31;
        int g0 = seg[n0];
        int g1 = seg[n1];
        float q0 = q[g0], y0 = y[n0];
        float q1 = q[g1], y1 = y[n1];

        float x0 = fmaf(y0, q0, -cB);
        float x1 = fmaf(y1, q1, -cB);
        int id0 = (int)(__float_as_uint(q0) >> 31);
        int id1 = (int)(__float_as_uint(q1) >> 31);
        int b0 = min(max((int)floorf(x0), 0), TROWS - 2);
        int b1 = min(max((int)floorf(x1), 0), TROWS - 2);
        float t0 = x0 - (float)b0;
        float t1 = x1 - (float)b1;

        const f32x4* r00 = (const f32x4*)&tbl[(long)((id0 << 10) + b0) * FDIM];
        const f32x4* r01 = (const f32x4*)&tbl[(long)((id1 << 10) + b1) * FDIM];
        f32x4 a0 = r00[j0], c0 = r00[j0 + 32];
        f32x4 a1 = r01[j1], c1 = r01[j1 + 32];

        f32x4 o0, o1;
        o0[0] = a0[0] + t0 * (c0[0] - a0[0]);
        o0[1] = a0[1] + t0 * (c0[1] - a0[1]);
        o0[2] = a0[2] + t0 * (c0[2] - a0[2]);
        o0[3] = a0[3] + t0 * (c0[3] - a0[3]);
        o1[0] = a1[0] + t1 * (c1[0] - a1[0]);
        o1[1] = a1[1] + t1 * (c1[1] - a1[1]);
        o1[2] = a1[2] + t1 * (c1[2] - a1[2]);
        o1[3] = a1[3] + t1 * (c1[3] - a1[3]);
        __builtin_nontemporal_store(o0, (f32x4*)&out[(long)n0 * FDIM + j0 * 4]);
        __builtin_nontemporal_store(o1, (f32x4*)&out[(long)n1 * FDIM + j1 * 4]);
    }
}

// ---------------------------------------------------------------------------
extern "C" void kernel_launch(void* const* d_in, const int* in_sizes, int n_in,
                              void* d_out, int out_size, void* d_ws, size_t ws_size,
                              hipStream_t stream) {
    const float* onehot = (const float*)d_in[0];
    const float* psi    = (const float*)d_in[1];
    const float* Wq     = (const float*)d_in[2];
    const float* Wk     = (const float*)d_in[3];
    const float* Wv     = (const float*)d_in[4];
    const float* W1     = (const float*)d_in[5];
    const float* W2     = (const float*)d_in[6];
    const int*   seg    = (const int*)d_in[7];
    float*       out    = (float*)d_out;

    // workspace layout (tbl aliases z: z is dead after stat_kernel)
    char* ws = (char*)d_ws;
    float*    denom = (float*)ws;                         // 32KB
    unsigned* ymaxE = (unsigned*)(ws + 32768);            // 32KB
    unsigned* yminE = (unsigned*)(ws + 65536);            // 32KB
    float*    T     = (float*)(ws + 98304);               // 1KB
    float*    prm   = (float*)(ws + 99328);               // 16B
    float*    q     = (float*)(ws + 100352);              // 32KB
    float*    y     = (float*)(ws + 133120);              // 1MB
    int*      z     = (int*)(ws + 133120 + NATOMS * 4);   // 1MB
    float*    tbl   = (float*)(ws + 133120 + NATOMS * 4); // 1MB (alias z)

    zscan_prep_kernel<<<NBLK_SCAN + 97, 256, 0, stream>>>(
        (const f32x4*)onehot, z, Wq, Wk, T, denom, yminE, ymaxE);

    stat_kernel<<<NATOMS / 256, 256, 0, stream>>>(seg, psi, T, z, y,
                                                  denom, yminE, ymaxE);

    mlp_table_kernel<<<2 * TROWS / 128, 512, 0, stream>>>(psi, denom, yminE, ymaxE,
                                                          Wv, W1, W2, tbl, prm, q);

    interp_kernel<<<INTERP_BLOCKS, 256, 0, stream>>>(seg, y, q, prm, tbl, out);
}

// Round 14
// 74.525 us; speedup vs baseline: 1.1665x; 1.1234x over previous
//
#include <hip/hip_runtime.h>
#include <hip/hip_bf16.h>

#define NATOMS 262144
#define NG     8192
#define FDIM   128
#define NELEM  118
#define EPS    1e-6f
#define TROWS  1024          // table rows per idx (1023 intervals)
#define NBLK_SCAN 7552       // 7552 * 1024 float4 = 7,733,248 = NATOMS*NELEM/4

typedef __attribute__((ext_vector_type(8))) short bf16x8;
typedef __attribute__((ext_vector_type(4))) float f32x4;

__device__ __forceinline__ float silu_fast(float v) {
    return v * __builtin_amdgcn_rcpf(1.f + __expf(-v));
}
// truncation-based hi/lo split of two floats -> packed u32 (hi pair, lo pair)
__device__ __forceinline__ void split2(float x0, float x1,
                                       unsigned& hpack, unsigned& lpack) {
    unsigned u0 = __float_as_uint(x0), u1 = __float_as_uint(x1);
    unsigned h0m = u0 & 0xFFFF0000u, h1m = u1 & 0xFFFF0000u;
    hpack = (u0 >> 16) | h1m;
    float l0 = x0 - __uint_as_float(h0m);
    float l1 = x1 - __uint_as_float(h1m);
    lpack = (__float_as_uint(l0) >> 16) | (__float_as_uint(l1) & 0xFFFF0000u);
}
// swizzled LDS offset (u16 elems): row stride 128, 16B-granule XOR swizzle
__device__ __forceinline__ int aoff(int row, int k) {
    return row * FDIM + ((((k >> 3) ^ row) & 15) << 3) + (k & 7);
}

// ---------------------------------------------------------------------------
// Dispatch 1: blocks 0..7551 = z-scan (4 independent NT float4 per thread);
// tail blocks = prep (softplus T, denom/ymin/ymax init).  [R11-proven]
// ---------------------------------------------------------------------------
__global__ void zscan_prep_kernel(const f32x4* __restrict__ onehot4,
                                  int* __restrict__ z,
                                  const float* __restrict__ Wq,
                                  const float* __restrict__ Wk,
                                  float* __restrict__ T,
                                  float* __restrict__ denom,
                                  unsigned* __restrict__ yminE,
                                  unsigned* __restrict__ ymaxE) {
    int b = blockIdx.x, t = threadIdx.x;
    if (b < NBLK_SCAN) {
        int base = b * 1024 + t;
        f32x4 v[4];
        #pragma unroll
        for (int k = 0; k < 4; ++k)
            v[k] = __builtin_nontemporal_load(&onehot4[base + k * 256]);
        #pragma unroll
        for (int k = 0; k < 4; ++k) {
            int i4 = (base + k * 256) * 4;
            #pragma unroll
            for (int q = 0; q < 4; ++q)
                if (v[k][q] > 0.5f) {
                    int gf = i4 + q;
                    int n  = gf / NELEM;
                    z[n] = gf - n * NELEM;
                }
        }
    } else {
        int pb = b - NBLK_SCAN;
        if (pb == 0) {
            if (t < 2 * NELEM) {
                int idx = t / NELEM;
                int zz  = t - idx * NELEM;
                float dot = 0.f;
                #pragma unroll 8
                for (int f = 0; f < FDIM; ++f)
                    dot += Wq[f * NELEM + zz] * Wk[idx * FDIM + f];
                float x = dot * 0.08838834764831843f;  // 1/sqrt(128)
                T[t] = fmaxf(x, 0.f) + log1pf(expf(-fabsf(x)));
            }
        } else {
            int j = (pb - 1) * 256 + t; // 0..24575
            if (j < NG)            denom[j] = 0.f;
            else if (j < 2 * NG)   ymaxE[j - NG] = 0u;               // y > 0
            else                   yminE[j - 2 * NG] = 0xFFFFFFFFu;  // raw max
        }
    }
}

// ---------------------------------------------------------------------------
// Dispatch 2: y[n] = T[idx(g)][z[n]] (coalesced); segmented {sum,min,max}
// per graph via wave scan; spread boundary atomics.  [R11-proven]
// ---------------------------------------------------------------------------
__global__ void stat_kernel(const int* __restrict__ seg,
                            const float* __restrict__ psi,
                            const float* __restrict__ T,
                            const int* __restrict__ z,
                            float* __restrict__ y_out,
                            float* __restrict__ denom,
                            unsigned* __restrict__ yminE,
                            unsigned* __restrict__ ymaxE) {
    int n = blockIdx.x * blockDim.x + threadIdx.x;
    int g = seg[n];
    int idx = psi[g] < 0.f ? 1 : 0;
    float yv = T[idx * NELEM + z[n]];
    y_out[n] = yv;

    int lane = threadIdx.x & 63;
    float s = yv, mn = yv, mx = yv;
    #pragma unroll
    for (int d = 1; d < 64; d <<= 1) {
        float os = __shfl_up(s,  (unsigned)d, 64);
        float on = __shfl_up(mn, (unsigned)d, 64);
        float ox = __shfl_up(mx, (unsigned)d, 64);
        int   go = __shfl_up(g,  (unsigned)d, 64);
        if (lane >= d && go == g) {
            s += os;
            mn = fminf(mn, on);
            mx = fmaxf(mx, ox);
        }
    }
    int gn = __shfl_down(g, 1u, 64);
    if (lane == 63 || gn != g) {
        atomicAdd(&denom[g], s);
        atomicMin(&yminE[g], __float_as_uint(mn));   // y > 0: raw-uint order ok
        atomicMax(&ymaxE[g], __float_as_uint(mx));
    }
}

// ---------------------------------------------------------------------------
// Dispatch 3: range-reduce prologue (redundant per block) -> prm; write
// q[g] = psi/(denom+eps)*p2 (16 blk x 512 thr = 8192); split-bf16 MFMA MLP
// over 2048 virtual atoms -> tbl. Weights split to bf16 hi/lo in registers.
// ---------------------------------------------------------------------------
__launch_bounds__(512, 4)
__global__ void mlp_table_kernel(const float* __restrict__ psi_g,
                                 const float* __restrict__ denom,
                                 const unsigned* __restrict__ yminE,
                                 const unsigned* __restrict__ ymaxE,
                                 const float* __restrict__ Wv,
                                 const float* __restrict__ W1,
                                 const float* __restrict__ W2,
                                 float* __restrict__ tbl,
                                 float* __restrict__ prm,
                                 float* __restrict__ q) {
    __shared__ __align__(16) unsigned short Ahi[FDIM * FDIM];
    __shared__ __align__(16) unsigned short Alo[FDIM * FDIM];
    __shared__ float att_s[128];
    __shared__ int   idx_s[128];
    __shared__ float wv_s[2 * FDIM];
    __shared__ float smn[8], smx[8], prm_s[3];

    int t    = threadIdx.x;
    int lane = t & 63;
    int w    = t >> 6;

    // ---- range reduction over graphs (identical in every block) ----
    {
        float mn = 1e30f, mx = -1e30f;
        for (int j = t; j < NG; j += 512) {
            unsigned me = yminE[j];
            if (me != 0xFFFFFFFFu) {           // graph has atoms
                float r  = __builtin_amdgcn_rcpf(denom[j] + EPS);
                float ps = psi_g[j];
                float a1 = ps * __uint_as_float(me) * r;
                float a2 = ps * __uint_as_float(ymaxE[j]) * r;
                mn = fminf(mn, fminf(a1, a2));
                mx = fmaxf(mx, fmaxf(a1, a2));
            }
        }
        #pragma unroll
        for (int d = 32; d > 0; d >>= 1) {
            mn = fminf(mn, __shfl_xor(mn, d, 64));
            mx = fmaxf(mx, __shfl_xor(mx, d, 64));
        }
        if (lane == 0) { smn[w] = mn; smx[w] = mx; }
        __syncthreads();
        if (t == 0) {
            mn = smn[0]; mx = smx[0];
            #pragma unroll
            for (int qq = 1; qq < 8; ++qq) {
                mn = fminf(mn, smn[qq]);
                mx = fmaxf(mx, smx[qq]);
            }
            float range = mx - mn;
            if (!(range > 0.f)) range = 1.f;
            float p2 = (float)(TROWS - 1) / range;
            prm_s[0] = mn;
            prm_s[1] = range / (float)(TROWS - 1);
            prm_s[2] = p2;
            if (blockIdx.x == 0) {
                prm[0] = mn;
                prm[1] = prm_s[1];
                prm[2] = p2;
                prm[3] = mn * p2;   // cB
            }
        }
        __syncthreads();
    }
    float p0 = prm_s[0], hh = prm_s[1], p2 = prm_s[2];

    // ---- q[g] write: 16 blocks x 512 threads = 8192 graphs ----
    {
        int g = blockIdx.x * 512 + t;
        q[g] = psi_g[g] * __builtin_amdgcn_rcpf(denom[g] + EPS) * p2;
    }

    int wr   = w >> 2;
    int wc   = w & 3;
    int n0   = blockIdx.x * 128;
    int rbase = wr * 64;
    int jbase = wc * 32;

    if (t < 256) wv_s[t] = Wv[t];
    if (t >= 256 && t < 384) {
        int a = t - 256;
        int n = n0 + a;
        idx_s[a] = n >> 10;
        att_s[a] = p0 + (float)(n & (TROWS - 1)) * hh;
    }
    __syncthreads();

    {
        int a  = t >> 2;
        int kq = (t & 3) * 32;
        float att = att_s[a];
        const float* wvp = &wv_s[idx_s[a] * FDIM + kq];
        #pragma unroll
        for (int kk = 0; kk < 32; kk += 2) {
            float s0 = silu_fast(att * wvp[kk]);
            float s1 = silu_fast(att * wvp[kk + 1]);
            unsigned hp, lp;
            split2(s0, s1, hp, lp);
            int off = aoff(a, kq + kk);
            *(unsigned*)&Ahi[off] = hp;
            *(unsigned*)&Alo[off] = lp;
        }
    }
    __syncthreads();

    int lrow = lane & 15;
    int k0   = (lane >> 4) * 8;

    f32x4 acc[4][2];

    #pragma unroll
    for (int L = 0; L < 2; ++L) {
        const float* Wf = (L == 0) ? W1 : W2;

        #pragma unroll
        for (int mt = 0; mt < 4; ++mt)
            #pragma unroll
            for (int jt = 0; jt < 2; ++jt)
                acc[mt][jt] = (f32x4){0.f, 0.f, 0.f, 0.f};

        #pragma unroll
        for (int kt = 0; kt < 4; ++kt) {
            bf16x8 bh[2], bl[2];
            #pragma unroll
            for (int jt = 0; jt < 2; ++jt) {
                int j = jbase + jt * 16 + lrow;
                const f32x4* wp = (const f32x4*)&Wf[j * FDIM + kt * 32 + k0];
                f32x4 wa = wp[0], wb = wp[1];
                union { unsigned u[4]; bf16x8 v; } H, L8;
                split2(wa[0], wa[1], H.u[0], L8.u[0]);
                split2(wa[2], wa[3], H.u[1], L8.u[1]);
                split2(wb[0], wb[1], H.u[2], L8.u[2]);
                split2(wb[2], wb[3], H.u[3], L8.u[3]);
                bh[jt] = H.v; bl[jt] = L8.v;
            }
            #pragma unroll
            for (int mt = 0; mt < 4; ++mt) {
                int off = aoff(rbase + mt * 16 + lrow, kt * 32 + k0);
                bf16x8 ah = *(const bf16x8*)&Ahi[off];
                bf16x8 al = *(const bf16x8*)&Alo[off];
                #pragma unroll
                for (int jt = 0; jt < 2; ++jt) {
                    acc[mt][jt] = __builtin_amdgcn_mfma_f32_16x16x32_bf16(ah, bh[jt], acc[mt][jt], 0, 0, 0);
                    acc[mt][jt] = __builtin_amdgcn_mfma_f32_16x16x32_bf16(ah, bl[jt], acc[mt][jt], 0, 0, 0);
                    acc[mt][jt] = __builtin_amdgcn_mfma_f32_16x16x32_bf16(al, bh[jt], acc[mt][jt], 0, 0, 0);
                }
            }
        }

        if (L == 0) {
            __syncthreads();
            #pragma unroll
            for (int mt = 0; mt < 4; ++mt)
                #pragma unroll
                for (int jt = 0; jt < 2; ++jt)
                    #pragma unroll
                    for (int r = 0; r < 4; ++r) {
                        int row = rbase + mt * 16 + (lane >> 4) * 4 + r;
                        int col = jbase + jt * 16 + lrow;
                        float s = silu_fast(acc[mt][jt][r]);
                        unsigned u = __float_as_uint(s);
                        unsigned hm = u & 0xFFFF0000u;
                        float l = s - __uint_as_float(hm);
                        int off = aoff(row, col);
                        Ahi[off] = (unsigned short)(u >> 16);
                        Alo[off] = (unsigned short)(__float_as_uint(l) >> 16);
                    }
            __syncthreads();
        }
    }

    // tbl row = f(att) = v_att + h2
    #pragma unroll
    for (int mt = 0; mt < 4; ++mt)
        #pragma unroll
        for (int jt = 0; jt < 2; ++jt) {
            int row0 = rbase + mt * 16 + (lane >> 4) * 4;
            int col  = jbase + jt * 16 + lrow;
            float* p = tbl + (long)(n0 + row0) * FDIM + col;
            #pragma unroll
            for (int r = 0; r < 4; ++r) {
                int row = row0 + r;
                float vatt = att_s[row] * wv_s[idx_s[row] * FDIM + col];
                p[r * FDIM] = acc[mt][jt][r] + vatt;
            }
        }
}

// ---------------------------------------------------------------------------
// Dispatch 4: out[n][:] = lerp(tbl[idx][b], tbl[idx][b+1], t). 32 lanes/atom.
// Runtime grid-stride loop (R11-proven: opaque trip count keeps it a real
// loop -> low VGPR, high occupancy; full unrolls regressed in R12/R13).
// ---------------------------------------------------------------------------
__global__ void interp_kernel(const int* __restrict__ seg,
                              const float* __restrict__ y,
                              const float* __restrict__ q,
                              const float* __restrict__ prm,
                              const float* __restrict__ tbl,
                              float* __restrict__ out) {
    const int total = NATOMS * 32;
    float cB = prm[3];
    int stride = gridDim.x * blockDim.x;
    for (int i = blockIdx.x * blockDim.x + threadIdx.x; i < total; i += stride) {
        int n  = i >> 5;
        int jq = i & 31;
        int g  = seg[n];
        float qv = q[g];
        float x  = fmaf(y[n], qv, -cB);
        int idx  = (int)(__float_as_uint(qv) >> 31);
        int b = (int)floorf(x);
        b = min(max(b, 0), TROWS - 2);
        float t = x - (float)b;
        const f32x4* r0 = (const f32x4*)&tbl[(long)((idx << 10) + b) * FDIM];
        f32x4 a = r0[jq];
        f32x4 c = r0[jq + 32];   // next row (+128 floats)
        f32x4 o;
        o[0] = a[0] + t * (c[0] - a[0]);
        o[1] = a[1] + t * (c[1] - a[1]);
        o[2] = a[2] + t * (c[2] - a[2]);
        o[3] = a[3] + t * (c[3] - a[3]);
        __builtin_nontemporal_store(o, (f32x4*)&out[(long)n * FDIM + jq * 4]);
    }
}

// ---------------------------------------------------------------------------
extern "C" void kernel_launch(void* const* d_in, const int* in_sizes, int n_in,
                              void* d_out, int out_size, void* d_ws, size_t ws_size,
                              hipStream_t stream) {
    const float* onehot = (const float*)d_in[0];
    const float* psi    = (const float*)d_in[1];
    const float* Wq     = (const float*)d_in[2];
    const float* Wk     = (const float*)d_in[3];
    const float* Wv     = (const float*)d_in[4];
    const float* W1     = (const float*)d_in[5];
    const float* W2     = (const float*)d_in[6];
    const int*   seg    = (const int*)d_in[7];
    float*       out    = (float*)d_out;

    // workspace layout (tbl aliases z: z is dead after stat_kernel)
    char* ws = (char*)d_ws;
    float*    denom = (float*)ws;                         // 32KB
    unsigned* ymaxE = (unsigned*)(ws + 32768);            // 32KB
    unsigned* yminE = (unsigned*)(ws + 65536);            // 32KB
    float*    T     = (float*)(ws + 98304);               // 1KB
    float*    prm   = (float*)(ws + 99328);               // 16B
    float*    q     = (float*)(ws + 100352);              // 32KB
    float*    y     = (float*)(ws + 133120);              // 1MB
    int*      z     = (int*)(ws + 133120 + NATOMS * 4);   // 1MB
    float*    tbl   = (float*)(ws + 133120 + NATOMS * 4); // 1MB (alias z)

    zscan_prep_kernel<<<NBLK_SCAN + 97, 256, 0, stream>>>(
        (const f32x4*)onehot, z, Wq, Wk, T, denom, yminE, ymaxE);

    stat_kernel<<<NATOMS / 256, 256, 0, stream>>>(seg, psi, T, z, y,
                                                  denom, yminE, ymaxE);

    mlp_table_kernel<<<2 * TROWS / 128, 512, 0, stream>>>(psi, denom, yminE, ymaxE,
                                                          Wv, W1, W2, tbl, prm, q);

    interp_kernel<<<4096, 256, 0, stream>>>(seg, y, q, prm, tbl, out);
}

// Round 16
// 74.473 us; speedup vs baseline: 1.1673x; 1.0007x over previous
//
#include <hip/hip_runtime.h>
#include <hip/hip_bf16.h>

#define NATOMS 262144
#define NG     8192
#define FDIM   128
#define NELEM  118
#define EPS    1e-6f
#define TROWS  1024          // table rows per idx (1023 intervals)
#define NBLK_SCAN 7552       // 7552 * 1024 float4 = 7,733,248 = NATOMS*NELEM/4

typedef __attribute__((ext_vector_type(8))) short bf16x8;
typedef __attribute__((ext_vector_type(4))) float f32x4;

__device__ __forceinline__ float silu_fast(float v) {
    return v * __builtin_amdgcn_rcpf(1.f + __expf(-v));
}
// truncation-based hi/lo split of two floats -> packed u32 (hi pair, lo pair)
__device__ __forceinline__ void split2(float x0, float x1,
                                       unsigned& hpack, unsigned& lpack) {
    unsigned u0 = __float_as_uint(x0), u1 = __float_as_uint(x1);
    unsigned h0m = u0 & 0xFFFF0000u, h1m = u1 & 0xFFFF0000u;
    hpack = (u0 >> 16) | h1m;
    float l0 = x0 - __uint_as_float(h0m);
    float l1 = x1 - __uint_as_float(h1m);
    lpack = (__float_as_uint(l0) >> 16) | (__float_as_uint(l1) & 0xFFFF0000u);
}
// swizzled LDS offset (u16 elems): row stride 128, 16B-granule XOR swizzle
__device__ __forceinline__ int aoff(int row, int k) {
    return row * FDIM + ((((k >> 3) ^ row) & 15) << 3) + (k & 7);
}

// ---------------------------------------------------------------------------
// Dispatch 1: blocks 0..7551 = z-scan (4 independent NT float4 per thread);
// tail blocks = prep (softplus T, denom/ymin/ymax init).  [R11/R14-proven]
// ---------------------------------------------------------------------------
__global__ void zscan_prep_kernel(const f32x4* __restrict__ onehot4,
                                  int* __restrict__ z,
                                  const float* __restrict__ Wq,
                                  const float* __restrict__ Wk,
                                  float* __restrict__ T,
                                  float* __restrict__ denom,
                                  unsigned* __restrict__ yminE,
                                  unsigned* __restrict__ ymaxE) {
    int b = blockIdx.x, t = threadIdx.x;
    if (b < NBLK_SCAN) {
        int base = b * 1024 + t;
        f32x4 v[4];
        #pragma unroll
        for (int k = 0; k < 4; ++k)
            v[k] = __builtin_nontemporal_load(&onehot4[base + k * 256]);
        #pragma unroll
        for (int k = 0; k < 4; ++k) {
            int i4 = (base + k * 256) * 4;
            #pragma unroll
            for (int q = 0; q < 4; ++q)
                if (v[k][q] > 0.5f) {
                    int gf = i4 + q;
                    int n  = gf / NELEM;
                    z[n] = gf - n * NELEM;
                }
        }
    } else {
        int pb = b - NBLK_SCAN;
        if (pb == 0) {
            if (t < 2 * NELEM) {
                int idx = t / NELEM;
                int zz  = t - idx * NELEM;
                float dot = 0.f;
                #pragma unroll 8
                for (int f = 0; f < FDIM; ++f)
                    dot += Wq[f * NELEM + zz] * Wk[idx * FDIM + f];
                float x = dot * 0.08838834764831843f;  // 1/sqrt(128)
                T[t] = fmaxf(x, 0.f) + log1pf(expf(-fabsf(x)));
            }
        } else {
            int j = (pb - 1) * 256 + t; // 0..24575
            if (j < NG)            denom[j] = 0.f;
            else if (j < 2 * NG)   ymaxE[j - NG] = 0u;               // y > 0
            else                   yminE[j - 2 * NG] = 0xFFFFFFFFu;  // raw max
        }
    }
}

// ---------------------------------------------------------------------------
// Dispatch 2: y[n] = T[idx(g)][z[n]] (coalesced); segmented {sum,min,max}
// per graph via wave scan; spread boundary atomics.  [R11/R14-proven]
// ---------------------------------------------------------------------------
__global__ void stat_kernel(const int* __restrict__ seg,
                            const float* __restrict__ psi,
                            const float* __restrict__ T,
                            const int* __restrict__ z,
                            float* __restrict__ y_out,
                            float* __restrict__ denom,
                            unsigned* __restrict__ yminE,
                            unsigned* __restrict__ ymaxE) {
    int n = blockIdx.x * blockDim.x + threadIdx.x;
    int g = seg[n];
    int idx = psi[g] < 0.f ? 1 : 0;
    float yv = T[idx * NELEM + z[n]];
    y_out[n] = yv;

    int lane = threadIdx.x & 63;
    float s = yv, mn = yv, mx = yv;
    #pragma unroll
    for (int d = 1; d < 64; d <<= 1) {
        float os = __shfl_up(s,  (unsigned)d, 64);
        float on = __shfl_up(mn, (unsigned)d, 64);
        float ox = __shfl_up(mx, (unsigned)d, 64);
        int   go = __shfl_up(g,  (unsigned)d, 64);
        if (lane >= d && go == g) {
            s += os;
            mn = fminf(mn, on);
            mx = fmaxf(mx, ox);
        }
    }
    int gn = __shfl_down(g, 1u, 64);
    if (lane == 63 || gn != g) {
        atomicAdd(&denom[g], s);
        atomicMin(&yminE[g], __float_as_uint(mn));   // y > 0: raw-uint order ok
        atomicMax(&ymaxE[g], __float_as_uint(mx));
    }
}

// ---------------------------------------------------------------------------
// Dispatch 3: range-reduce prologue (redundant per block) -> prm; write
// q[g] = psi/(denom+eps)*p2 (16 blk x 512 thr = 8192); split-bf16 MFMA MLP
// over 2048 virtual atoms -> tbl. Weights split to bf16 hi/lo in registers.
// ---------------------------------------------------------------------------
__launch_bounds__(512, 4)
__global__ void mlp_table_kernel(const float* __restrict__ psi_g,
                                 const float* __restrict__ denom,
                                 const unsigned* __restrict__ yminE,
                                 const unsigned* __restrict__ ymaxE,
                                 const float* __restrict__ Wv,
                                 const float* __restrict__ W1,
                                 const float* __restrict__ W2,
                                 float* __restrict__ tbl,
                                 float* __restrict__ prm,
                                 float* __restrict__ q) {
    __shared__ __align__(16) unsigned short Ahi[FDIM * FDIM];
    __shared__ __align__(16) unsigned short Alo[FDIM * FDIM];
    __shared__ float att_s[128];
    __shared__ int   idx_s[128];
    __shared__ float wv_s[2 * FDIM];
    __shared__ float smn[8], smx[8], prm_s[3];

    int t    = threadIdx.x;
    int lane = t & 63;
    int w    = t >> 6;

    // ---- range reduction over graphs (identical in every block) ----
    {
        float mn = 1e30f, mx = -1e30f;
        for (int j = t; j < NG; j += 512) {
            unsigned me = yminE[j];
            if (me != 0xFFFFFFFFu) {           // graph has atoms
                float r  = __builtin_amdgcn_rcpf(denom[j] + EPS);
                float ps = psi_g[j];
                float a1 = ps * __uint_as_float(me) * r;
                float a2 = ps * __uint_as_float(ymaxE[j]) * r;
                mn = fminf(mn, fminf(a1, a2));
                mx = fmaxf(mx, fmaxf(a1, a2));
            }
        }
        #pragma unroll
        for (int d = 32; d > 0; d >>= 1) {
            mn = fminf(mn, __shfl_xor(mn, d, 64));
            mx = fmaxf(mx, __shfl_xor(mx, d, 64));
        }
        if (lane == 0) { smn[w] = mn; smx[w] = mx; }
        __syncthreads();
        if (t == 0) {
            mn = smn[0]; mx = smx[0];
            #pragma unroll
            for (int qq = 1; qq < 8; ++qq) {
                mn = fminf(mn, smn[qq]);
                mx = fmaxf(mx, smx[qq]);
            }
            float range = mx - mn;
            if (!(range > 0.f)) range = 1.f;
            float p2 = (float)(TROWS - 1) / range;
            prm_s[0] = mn;
            prm_s[1] = range / (float)(TROWS - 1);
            prm_s[2] = p2;
            if (blockIdx.x == 0) {
                prm[0] = mn;
                prm[1] = prm_s[1];
                prm[2] = p2;
                prm[3] = mn * p2;   // cB
            }
        }
        __syncthreads();
    }
    float p0 = prm_s[0], hh = prm_s[1], p2 = prm_s[2];

    // ---- q[g] write: 16 blocks x 512 threads = 8192 graphs ----
    {
        int g = blockIdx.x * 512 + t;
        q[g] = psi_g[g] * __builtin_amdgcn_rcpf(denom[g] + EPS) * p2;
    }

    int wr   = w >> 2;
    int wc   = w & 3;
    int n0   = blockIdx.x * 128;
    int rbase = wr * 64;
    int jbase = wc * 32;

    if (t < 256) wv_s[t] = Wv[t];
    if (t >= 256 && t < 384) {
        int a = t - 256;
        int n = n0 + a;
        idx_s[a] = n >> 10;
        att_s[a] = p0 + (float)(n & (TROWS - 1)) * hh;
    }
    __syncthreads();

    {
        int a  = t >> 2;
        int kq = (t & 3) * 32;
        float att = att_s[a];
        const float* wvp = &wv_s[idx_s[a] * FDIM + kq];
        #pragma unroll
        for (int kk = 0; kk < 32; kk += 2) {
            float s0 = silu_fast(att * wvp[kk]);
            float s1 = silu_fast(att * wvp[kk + 1]);
            unsigned hp, lp;
            split2(s0, s1, hp, lp);
            int off = aoff(a, kq + kk);
            *(unsigned*)&Ahi[off] = hp;
            *(unsigned*)&Alo[off] = lp;
        }
    }
    __syncthreads();

    int lrow = lane & 15;
    int k0   = (lane >> 4) * 8;

    f32x4 acc[4][2];

    #pragma unroll
    for (int L = 0; L < 2; ++L) {
        const float* Wf = (L == 0) ? W1 : W2;

        #pragma unroll
        for (int mt = 0; mt < 4; ++mt)
            #pragma unroll
            for (int jt = 0; jt < 2; ++jt)
                acc[mt][jt] = (f32x4){0.f, 0.f, 0.f, 0.f};

        #pragma unroll
        for (int kt = 0; kt < 4; ++kt) {
            bf16x8 bh[2], bl[2];
            #pragma unroll
            for (int jt = 0; jt < 2; ++jt) {
                int j = jbase + jt * 16 + lrow;
                const f32x4* wp = (const f32x4*)&Wf[j * FDIM + kt * 32 + k0];
                f32x4 wa = wp[0], wb = wp[1];
                union { unsigned u[4]; bf16x8 v; } H, L8;
                split2(wa[0], wa[1], H.u[0], L8.u[0]);
                split2(wa[2], wa[3], H.u[1], L8.u[1]);
                split2(wb[0], wb[1], H.u[2], L8.u[2]);
                split2(wb[2], wb[3], H.u[3], L8.u[3]);
                bh[jt] = H.v; bl[jt] = L8.v;
            }
            #pragma unroll
            for (int mt = 0; mt < 4; ++mt) {
                int off = aoff(rbase + mt * 16 + lrow, kt * 32 + k0);
                bf16x8 ah = *(const bf16x8*)&Ahi[off];
                bf16x8 al = *(const bf16x8*)&Alo[off];
                #pragma unroll
                for (int jt = 0; jt < 2; ++jt) {
                    acc[mt][jt] = __builtin_amdgcn_mfma_f32_16x16x32_bf16(ah, bh[jt], acc[mt][jt], 0, 0, 0);
                    acc[mt][jt] = __builtin_amdgcn_mfma_f32_16x16x32_bf16(ah, bl[jt], acc[mt][jt], 0, 0, 0);
                    acc[mt][jt] = __builtin_amdgcn_mfma_f32_16x16x32_bf16(al, bh[jt], acc[mt][jt], 0, 0, 0);
                }
            }
        }

        if (L == 0) {
            __syncthreads();
            #pragma unroll
            for (int mt = 0; mt < 4; ++mt)
                #pragma unroll
                for (int jt = 0; jt < 2; ++jt)
                    #pragma unroll
                    for (int r = 0; r < 4; ++r) {
                        int row = rbase + mt * 16 + (lane >> 4) * 4 + r;
                        int col = jbase + jt * 16 + lrow;
                        float s = silu_fast(acc[mt][jt][r]);
                        unsigned u = __float_as_uint(s);
                        unsigned hm = u & 0xFFFF0000u;
                        float l = s - __uint_as_float(hm);
                        int off = aoff(row, col);
                        Ahi[off] = (unsigned short)(u >> 16);
                        Alo[off] = (unsigned short)(__float_as_uint(l) >> 16);
                    }
            __syncthreads();
        }
    }

    // tbl row = f(att) = v_att + h2
    #pragma unroll
    for (int mt = 0; mt < 4; ++mt)
        #pragma unroll
        for (int jt = 0; jt < 2; ++jt) {
            int row0 = rbase + mt * 16 + (lane >> 4) * 4;
            int col  = jbase + jt * 16 + lrow;
            float* p = tbl + (long)(n0 + row0) * FDIM + col;
            #pragma unroll
            for (int r = 0; r < 4; ++r) {
                int row = row0 + r;
                float vatt = att_s[row] * wv_s[idx_s[row] * FDIM + col];
                p[r * FDIM] = acc[mt][jt][r] + vatt;
            }
        }
}

// ---------------------------------------------------------------------------
// Dispatch 4: out[n][:] = lerp(tbl[idx][b], tbl[idx][b+1], t). 32 lanes/atom.
// Runtime grid-stride loop (R11/R14-proven: opaque trip count keeps it a real
// loop -> low VGPR, high occupancy; full unrolls regressed in R12/R13).
// ---------------------------------------------------------------------------
__global__ void interp_kernel(const int* __restrict__ seg,
                              const float* __restrict__ y,
                              const float* __restrict__ q,
                              const float* __restrict__ prm,
                              const float* __restrict__ tbl,
                              float* __restrict__ out) {
    const int total = NATOMS * 32;
    float cB = prm[3];
    int stride = gridDim.x * blockDim.x;
    for (int i = blockIdx.x * blockDim.x + threadIdx.x; i < total; i += stride) {
        int n  = i >> 5;
        int jq = i & 31;
        int g  = seg[n];
        float qv = q[g];
        float x  = fmaf(y[n], qv, -cB);
        int idx  = (int)(__float_as_uint(qv) >> 31);
        int b = (int)floorf(x);
        b = min(max(b, 0), TROWS - 2);
        float t = x - (float)b;
        const f32x4* r0 = (const f32x4*)&tbl[(long)((idx << 10) + b) * FDIM];
        f32x4 a = r0[jq];
        f32x4 c = r0[jq + 32];   // next row (+128 floats)
        f32x4 o;
        o[0] = a[0] + t * (c[0] - a[0]);
        o[1] = a[1] + t * (c[1] - a[1]);
        o[2] = a[2] + t * (c[2] - a[2]);
        o[3] = a[3] + t * (c[3] - a[3]);
        __builtin_nontemporal_store(o, (f32x4*)&out[(long)n * FDIM + jq * 4]);
    }
}

// ---------------------------------------------------------------------------
extern "C" void kernel_launch(void* const* d_in, const int* in_sizes, int n_in,
                              void* d_out, int out_size, void* d_ws, size_t ws_size,
                              hipStream_t stream) {
    const float* onehot = (const float*)d_in[0];
    const float* psi    = (const float*)d_in[1];
    const float* Wq     = (const float*)d_in[2];
    const float* Wk     = (const float*)d_in[3];
    const float* Wv     = (const float*)d_in[4];
    const float* W1     = (const float*)d_in[5];
    const float* W2     = (const float*)d_in[6];
    const int*   seg    = (const int*)d_in[7];
    float*       out    = (float*)d_out;

    // workspace layout (tbl aliases z: z is dead after stat_kernel)
    char* ws = (char*)d_ws;
    float*    denom = (float*)ws;                         // 32KB
    unsigned* ymaxE = (unsigned*)(ws + 32768);            // 32KB
    unsigned* yminE = (unsigned*)(ws + 65536);            // 32KB
    float*    T     = (float*)(ws + 98304);               // 1KB
    float*    prm   = (float*)(ws + 99328);               // 16B
    float*    q     = (float*)(ws + 100352);              // 32KB
    float*    y     = (float*)(ws + 133120);              // 1MB
    int*      z     = (int*)(ws + 133120 + NATOMS * 4);   // 1MB
    float*    tbl   = (float*)(ws + 133120 + NATOMS * 4); // 1MB (alias z)

    zscan_prep_kernel<<<NBLK_SCAN + 97, 256, 0, stream>>>(
        (const f32x4*)onehot, z, Wq, Wk, T, denom, yminE, ymaxE);

    stat_kernel<<<NATOMS / 256, 256, 0, stream>>>(seg, psi, T, z, y,
                                                  denom, yminE, ymaxE);

    mlp_table_kernel<<<2 * TROWS / 128, 512, 0, stream>>>(psi, denom, yminE, ymaxE,
                                                          Wv, W1, W2, tbl, prm, q);

    interp_kernel<<<4096, 256, 0, stream>>>(seg, y, q, prm, tbl, out);
}